// Round 2
// baseline (1087.326 us; speedup 1.0000x reference)
//
#include <hip/hip_runtime.h>
#include <math.h>

#define TT 512
#define BB 128
#define KK 9

// ---------------------------------------------------------------------------
// G: input projection for one time-chunk, both directions (grid.z = dir).
// Each block handles one timestep (128 batch rows) x 128 gates.
// dst[(tl*128 + b)*512 + g] = emb[x[b][t]] . w_ih[g] + b_ih[g] + b_hh[g]
// ---------------------------------------------------------------------------
__global__ __launch_bounds__(256) void input_gemm(
    const int* __restrict__ x, const float* __restrict__ emb,
    const float* __restrict__ w_ih_f, const float* __restrict__ w_ih_b,
    const float* __restrict__ b_ih_f, const float* __restrict__ b_hh_f,
    const float* __restrict__ b_ih_b, const float* __restrict__ b_hh_b,
    float* __restrict__ buf_f, float* __restrict__ buf_b,
    int t0f, int t0b)
{
    const int dir = blockIdx.z;
    const int s   = blockIdx.x;           // local timestep within chunk
    const int n0  = blockIdx.y * 128;     // gate tile base (0..384)
    const int t   = (dir ? t0b : t0f) + s;
    const float* w  = dir ? w_ih_b : w_ih_f;
    const float* bi = dir ? b_ih_b : b_ih_f;
    const float* bh = dir ? b_hh_b : b_hh_f;
    float* dst = dir ? buf_b : buf_f;

    __shared__ __align__(16) float As[8][132];
    __shared__ __align__(16) float Bs[8][132];
    __shared__ int tok[128];

    const int tid = threadIdx.x;
    if (tid < 128) tok[tid] = x[tid * TT + t];   // b = tid
    __syncthreads();

    const int tx = tid & 15;
    const int ty = tid >> 4;
    const int li = tid & 127;
    const int kb = (tid >> 7) * 4;   // 0 or 4

    const float* wrow = w + (size_t)(n0 + li) * 128;
    const float* arow = emb + (size_t)tok[li] * 128;

    float acc[8][8];
    #pragma unroll
    for (int i = 0; i < 8; i++)
        #pragma unroll
        for (int j = 0; j < 8; j++) acc[i][j] = 0.0f;

    for (int kc = 0; kc < 128; kc += 8) {
        const float4 a4 = *(const float4*)(arow + kc + kb);
        const float4 b4 = *(const float4*)(wrow + kc + kb);
        __syncthreads();
        As[kb + 0][li] = a4.x; As[kb + 1][li] = a4.y;
        As[kb + 2][li] = a4.z; As[kb + 3][li] = a4.w;
        Bs[kb + 0][li] = b4.x; Bs[kb + 1][li] = b4.y;
        Bs[kb + 2][li] = b4.z; Bs[kb + 3][li] = b4.w;
        __syncthreads();
        #pragma unroll
        for (int kk = 0; kk < 8; kk++) {
            float4 af0 = *(const float4*)&As[kk][ty * 8];
            float4 af1 = *(const float4*)&As[kk][ty * 8 + 4];
            float4 bf0 = *(const float4*)&Bs[kk][tx * 8];
            float4 bf1 = *(const float4*)&Bs[kk][tx * 8 + 4];
            float a_[8] = {af0.x, af0.y, af0.z, af0.w, af1.x, af1.y, af1.z, af1.w};
            float b_[8] = {bf0.x, bf0.y, bf0.z, bf0.w, bf1.x, bf1.y, bf1.z, bf1.w};
            #pragma unroll
            for (int i = 0; i < 8; i++)
                #pragma unroll
                for (int j = 0; j < 8; j++)
                    acc[i][j] += a_[i] * b_[j];
        }
    }

    const int nbase = n0 + tx * 8;        // gate index base within [0,512)
    float bias[8];
    #pragma unroll
    for (int j = 0; j < 8; j++) {
        int n = nbase + j;
        bias[j] = bi[n] + bh[n];
    }
    #pragma unroll
    for (int i = 0; i < 8; i++) {
        int b = ty * 8 + i;
        float* o = dst + ((size_t)s * 128 + b) * 512 + nbase;
        float4 v0, v1;
        v0.x = acc[i][0] + bias[0]; v0.y = acc[i][1] + bias[1];
        v0.z = acc[i][2] + bias[2]; v0.w = acc[i][3] + bias[3];
        v1.x = acc[i][4] + bias[4]; v1.y = acc[i][5] + bias[5];
        v1.z = acc[i][6] + bias[6]; v1.w = acc[i][7] + bias[7];
        *(float4*)o = v0;
        *(float4*)(o + 4) = v1;
    }
}

// ---------------------------------------------------------------------------
// L: LSTM recurrence over one chunk, both directions. One block per
// (dir, batch-row). Thread j owns gate j with w_hh[j][:] in 128 VGPRs.
// Emissions folded in: wave k computes tag-k partial emission per step.
// State (h,c) carried across chunk launches in global scratch.
// ---------------------------------------------------------------------------
__global__ __launch_bounds__(512) void lstm_chunk(
    const float* __restrict__ buf_f, const float* __restrict__ buf_b,
    const float* __restrict__ w_hh_f, const float* __restrict__ w_hh_b,
    const float* __restrict__ W_tag,
    float* __restrict__ em_f, float* __restrict__ em_b,
    float* __restrict__ h_state, float* __restrict__ c_state,
    int t0f, int t0b, int C, int init)
{
    const int dir = blockIdx.x >> 7;
    const int b   = blockIdx.x & 127;
    const int j   = threadIdx.x;
    const int wv  = j >> 6;      // wave id 0..7 == tag k
    const int ln  = j & 63;

    const float* whh = dir ? w_hh_b : w_hh_f;
    float w[128];
    #pragma unroll
    for (int q = 0; q < 32; q++) {
        float4 v = *(const float4*)(whh + (size_t)j * 128 + q * 4);
        w[4 * q + 0] = v.x; w[4 * q + 1] = v.y;
        w[4 * q + 2] = v.z; w[4 * q + 3] = v.w;
    }
    // emission weights: wave wv handles tag wv; wave 0 also tag 8
    const float wt0  = W_tag[wv * 256 + dir * 128 + ln];
    const float wt1  = W_tag[wv * 256 + dir * 128 + 64 + ln];
    const float wt8a = W_tag[8 * 256 + dir * 128 + ln];
    const float wt8b = W_tag[8 * 256 + dir * 128 + 64 + ln];

    __shared__ __align__(16) float h_lds[128];
    __shared__ float acts[512];
    float c = 0.0f;
    if (j < 128) {
        if (init) { h_lds[j] = 0.0f; }
        else {
            h_lds[j] = h_state[((size_t)dir * 128 + b) * 128 + j];
            c        = c_state[((size_t)dir * 128 + b) * 128 + j];
        }
    }
    __syncthreads();

    const float* buf = dir ? buf_b : buf_f;
    float* em        = dir ? em_b : em_f;
    const int t0     = dir ? t0b : t0f;
    const int  tl0   = dir ? (C - 1) : 0;
    const long lstep = dir ? -(long)(128 * 512) : (long)(128 * 512);

    const float* xp = buf + ((size_t)tl0 * 128 + b) * 512 + j;
    float xw = *xp;
    for (int s = 0; s < C; s++) {
        const int t = t0 + (dir ? (C - 1 - s) : s);
        const float* xpn = xp + lstep;
        float xw_next = (s + 1 < C) ? *xpn : 0.0f;

        float a0 = 0.f, a1 = 0.f, a2 = 0.f, a3 = 0.f;
        #pragma unroll
        for (int q = 0; q < 32; q++) {
            float4 h4 = *(const float4*)&h_lds[4 * q];
            a0 += w[4 * q + 0] * h4.x;
            a1 += w[4 * q + 1] * h4.y;
            a2 += w[4 * q + 2] * h4.z;
            a3 += w[4 * q + 3] * h4.w;
        }
        float pre = xw + ((a0 + a1) + (a2 + a3));

        float act;
        if ((j >> 7) == 2) act = tanhf(pre);                 // g gate
        else               act = 1.0f / (1.0f + expf(-pre)); // i, f, o
        acts[j] = act;
        __syncthreads();                 // acts ready; h_lds reads done

        if (j < 128) {
            float i_ = acts[j];
            float f_ = acts[128 + j];
            float g_ = acts[256 + j];
            float o_ = acts[384 + j];
            c = f_ * c + i_ * g_;
            h_lds[j] = o_ * tanhf(c);
        }
        __syncthreads();                 // h_lds = h_t

        // per-step partial emissions for this direction
        float h0 = h_lds[ln], h1 = h_lds[64 + ln];
        float p = h0 * wt0 + h1 * wt1;
        #pragma unroll
        for (int off = 32; off > 0; off >>= 1) p += __shfl_down(p, off);
        if (ln == 0) em[((size_t)t * BB + b) * KK + wv] = p;
        if (wv == 0) {
            float q8 = h0 * wt8a + h1 * wt8b;
            #pragma unroll
            for (int off = 32; off > 0; off >>= 1) q8 += __shfl_down(q8, off);
            if (ln == 0) em[((size_t)t * BB + b) * KK + 8] = q8;
        }

        xp = xpn;
        xw = xw_next;
    }

    if (j < 128) {
        h_state[((size_t)dir * 128 + b) * 128 + j] = h_lds[j];
        c_state[((size_t)dir * 128 + b) * 128 + j] = c;
    }
}

// ---------------------------------------------------------------------------
// V: Viterbi decode. One block (64 threads) per batch row; emissions and
// backpointers LDS-resident. First-max tie-break (ascending, strict >).
// ---------------------------------------------------------------------------
__global__ __launch_bounds__(64) void viterbi_kernel(
    const float* __restrict__ em_f, const float* __restrict__ em_b,
    const float* __restrict__ b_tag,
    const float* __restrict__ start_trans, const float* __restrict__ end_trans,
    const float* __restrict__ trans, int* __restrict__ out)
{
    const int b = blockIdx.x;
    const int lane = threadIdx.x;
    __shared__ float em_s[TT * KK];
    __shared__ unsigned char bp[TT][KK];

    float btg[KK];
    #pragma unroll
    for (int k = 0; k < KK; k++) btg[k] = b_tag[k];

    for (int f = lane; f < TT * KK; f += 64) {
        int t = f / KK, kk = f - t * KK;
        size_t off = ((size_t)t * BB + b) * KK + kk;
        em_s[f] = em_f[off] + em_b[off] + btg[kk];
    }
    __syncthreads();

    float trans_col[KK];
    float score = -1e30f;
    if (lane < KK) {
        #pragma unroll
        for (int i = 0; i < KK; i++) trans_col[i] = trans[i * KK + lane];
        score = start_trans[lane] + em_s[lane];
    }

    for (int t = 1; t < TT; t++) {
        float my = (lane < KK) ? score : -1e30f;
        float best = -1e30f;
        int bi = 0;
        #pragma unroll
        for (int i = 0; i < KK; i++) {
            float si = __shfl(my, i);
            float cand = si + trans_col[i];
            if (cand > best) { best = cand; bi = i; }
        }
        if (lane < KK) {
            bp[t][lane] = (unsigned char)bi;
            score = best + em_s[t * KK + lane];
        }
    }

    float fin = (lane < KK) ? (score + end_trans[lane]) : -1e30f;
    float bestf = -1e30f;
    int bj = 0;
    #pragma unroll
    for (int jx = 0; jx < KK; jx++) {
        float sj = __shfl(fin, jx);
        if (sj > bestf) { bestf = sj; bj = jx; }
    }

    if (lane == 0) {
        int tag = bj;
        out[b * TT + (TT - 1)] = tag;
        for (int t = TT - 1; t >= 1; t--) {
            tag = bp[t][tag];
            out[b * TT + t - 1] = tag;
        }
    }
}

// ---------------------------------------------------------------------------
extern "C" void kernel_launch(void* const* d_in, const int* in_sizes, int n_in,
                              void* d_out, int out_size, void* d_ws, size_t ws_size,
                              hipStream_t stream)
{
    const int*   x       = (const int*)  d_in[0];
    const float* emb     = (const float*)d_in[1];
    const float* w_ih_f  = (const float*)d_in[2];
    const float* w_hh_f  = (const float*)d_in[3];
    const float* b_ih_f  = (const float*)d_in[4];
    const float* b_hh_f  = (const float*)d_in[5];
    const float* w_ih_b  = (const float*)d_in[6];
    const float* w_hh_b  = (const float*)d_in[7];
    const float* b_ih_b  = (const float*)d_in[8];
    const float* b_hh_b  = (const float*)d_in[9];
    const float* W_tag   = (const float*)d_in[10];
    const float* b_tag   = (const float*)d_in[11];
    const float* start_t = (const float*)d_in[12];
    const float* end_t   = (const float*)d_in[13];
    const float* trans   = (const float*)d_in[14];
    int* out = (int*)d_out;

    // pick chunk size C based on available workspace
    const size_t em_elems    = (size_t)TT * BB * KK;   // 589824
    const size_t state_elems = (size_t)2 * 128 * 128;  // 32768 (per array)
    int C = 32;
    const int cands[4] = {512, 256, 128, 64};
    for (int ci = 0; ci < 4; ci++) {
        size_t need = ((size_t)2 * cands[ci] * BB * 512
                       + 2 * em_elems + 2 * state_elems) * sizeof(float);
        if (ws_size >= need) { C = cands[ci]; break; }
    }

    float* buf_f   = (float*)d_ws;                       // C*128*512
    float* buf_b   = buf_f + (size_t)C * BB * 512;       // C*128*512
    float* em_f    = buf_b + (size_t)C * BB * 512;       // T*B*9
    float* em_b    = em_f + em_elems;                    // T*B*9
    float* h_state = em_b + em_elems;                    // 2*128*128
    float* c_state = h_state + state_elems;              // 2*128*128

    const int rounds = TT / C;
    for (int r = 0; r < rounds; r++) {
        const int t0f = r * C;
        const int t0b = TT - (r + 1) * C;
        dim3 gg(C, 4, 2);
        input_gemm<<<gg, dim3(256), 0, stream>>>(
            x, emb, w_ih_f, w_ih_b, b_ih_f, b_hh_f, b_ih_b, b_hh_b,
            buf_f, buf_b, t0f, t0b);
        lstm_chunk<<<dim3(256), dim3(512), 0, stream>>>(
            buf_f, buf_b, w_hh_f, w_hh_b, W_tag, em_f, em_b,
            h_state, c_state, t0f, t0b, C, (r == 0) ? 1 : 0);
    }
    viterbi_kernel<<<dim3(BB), dim3(64), 0, stream>>>(
        em_f, em_b, b_tag, start_t, end_t, trans, out);
}